// Round 3
// baseline (226.490 us; speedup 1.0000x reference)
//
#include <hip/hip_runtime.h>

typedef __bf16 bf16;
typedef bf16 bf16x2 __attribute__((ext_vector_type(2)));
typedef bf16 bf16x4 __attribute__((ext_vector_type(4)));
typedef bf16 bf16x8 __attribute__((ext_vector_type(8)));
typedef float f32x4 __attribute__((ext_vector_type(4)));
typedef float4 f4;

constexpr int BHN = 64;   // B*H
constexpr int LN  = 4096;
constexpr int DN  = 64;
constexpr int MN  = 266;  // real feature rows
constexpr int MP  = 320;  // padded to 5*64 (zero proj rows; numerically negligible)
constexpr int STR = 72;   // LDS row stride in bf16
#define EPSF 1e-3f

// ---------------------------------------------------------------------------
// Kernel A: kvT[bh][d][m] = sum_l V[l][d]*kp[l][m],  ksum[bh][m] = sum_l kp[l][m]
//   kp[l][m] = relu(K[l][:]·proj[m][:]) + eps
// grid (8 l-chunks, 64 bh) x 256 threads; wave w owns m in [80w, 80w+80)
// Register-prefetch (T14): next tile's K/V loads issued during current MFMA phase.
// ---------------------------------------------------------------------------
__global__ __launch_bounds__(256, 2) void perf_kv_mfma(
    const float* __restrict__ kg, const float* __restrict__ vg,
    const float* __restrict__ proj, float* __restrict__ kv_ws,
    float* __restrict__ ksum_ws)
{
  __shared__ __align__(16) bf16 proj_lds[MP * STR];   // [m][d]
  __shared__ __align__(16) bf16 k_lds[64 * STR];      // [l][d]
  __shared__ __align__(16) bf16 vt_lds[64 * STR];     // [d][l]
  __shared__ __align__(16) bf16 kp_lds[4 * 16 * STR]; // per-wave [16 m][64 l]

  const int t    = threadIdx.x;
  const int wid  = t >> 6;
  const int lane = t & 63;
  const int c    = lane & 15;
  const int g    = lane >> 4;
  const int lsp  = blockIdx.x;  // 0..7
  const int bh   = blockIdx.y;  // 0..63

  // stage full proj -> bf16 LDS [m][d] (zero-padded m >= 266)
  const f4* projv = reinterpret_cast<const f4*>(proj);
  for (int idx = t; idx < MP * 16; idx += 256) {
    int m = idx >> 4, d4 = idx & 15;
    f4 val = {0.f, 0.f, 0.f, 0.f};
    if (m < MN) val = projv[m * 16 + d4];
    bf16x4 w = {(bf16)val.x, (bf16)val.y, (bf16)val.z, (bf16)val.w};
    *(bf16x4*)&proj_lds[m * STR + d4 * 4] = w;
  }

  f32x4 acc[4][5];
#pragma unroll
  for (int dt = 0; dt < 4; ++dt)
#pragma unroll
    for (int mt = 0; mt < 5; ++mt) acc[dt][mt] = (f32x4){0.f, 0.f, 0.f, 0.f};
  float ksum_acc[5] = {0.f, 0.f, 0.f, 0.f, 0.f};

  bf16* kpw = kp_lds + wid * 16 * STR;

  // prefetch registers
  f4 kreg[4];
  float vreg[16];
  const int vd = t & 63, vgrp = t >> 6;
  const f4* kgb = reinterpret_cast<const f4*>(kg) + ((size_t)bh * LN) * 16;
  const float* vgb = vg + ((size_t)bh * LN) * 64;

  auto LOADTILE = [&](int l0) {
#pragma unroll
    for (int i = 0; i < 4; ++i) kreg[i] = kgb[l0 * 16 + t + i * 256];
#pragma unroll
    for (int i = 0; i < 16; ++i) vreg[i] = vgb[(size_t)(l0 + vgrp * 16 + i) * 64 + vd];
  };
  auto WRITETILE = [&]() {
#pragma unroll
    for (int i = 0; i < 4; ++i) {
      int idx = t + i * 256;
      int l = idx >> 4, d4 = idx & 15;
      f4 val = kreg[i];
      bf16x4 w = {(bf16)val.x, (bf16)val.y, (bf16)val.z, (bf16)val.w};
      *(bf16x4*)&k_lds[l * STR + d4 * 4] = w;
    }
#pragma unroll
    for (int i4 = 0; i4 < 4; ++i4) {
      bf16x4 w = {(bf16)vreg[i4 * 4 + 0], (bf16)vreg[i4 * 4 + 1],
                  (bf16)vreg[i4 * 4 + 2], (bf16)vreg[i4 * 4 + 3]};
      *(bf16x4*)&vt_lds[vd * STR + vgrp * 16 + i4 * 4] = w;
    }
  };

  LOADTILE(lsp * 512);

  for (int ls = 0; ls < 8; ++ls) {
    __syncthreads();   // previous tile fully consumed
    WRITETILE();
    __syncthreads();   // tile (and, at ls=0, proj) ready
    if (ls < 7) LOADTILE(lsp * 512 + (ls + 1) * 64);  // overlap with MFMA phase

    bf16x8 va[4][2], ka[4][2];
#pragma unroll
    for (int dt = 0; dt < 4; ++dt)
#pragma unroll
      for (int s = 0; s < 2; ++s)
        va[dt][s] = *(const bf16x8*)&vt_lds[(dt * 16 + c) * STR + s * 32 + g * 8];
#pragma unroll
    for (int lt = 0; lt < 4; ++lt)
#pragma unroll
      for (int s = 0; s < 2; ++s)
        ka[lt][s] = *(const bf16x8*)&k_lds[(lt * 16 + c) * STR + s * 32 + g * 8];

#pragma unroll
    for (int mt = 0; mt < 5; ++mt) {
      const int m0 = wid * 80 + mt * 16;
      bf16x8 pb0 = *(const bf16x8*)&proj_lds[(m0 + c) * STR + g * 8];
      bf16x8 pb1 = *(const bf16x8*)&proj_lds[(m0 + c) * STR + 32 + g * 8];
      f32x4 fa[4];
#pragma unroll
      for (int lt = 0; lt < 4; ++lt) {
        fa[lt] = (f32x4){0.f, 0.f, 0.f, 0.f};
        fa[lt] = __builtin_amdgcn_mfma_f32_16x16x32_bf16(ka[lt][0], pb0, fa[lt], 0, 0, 0);
        fa[lt] = __builtin_amdgcn_mfma_f32_16x16x32_bf16(ka[lt][1], pb1, fa[lt], 0, 0, 0);
      }
      float kpart = 0.f;
#pragma unroll
      for (int lt = 0; lt < 4; ++lt) {
        f32x4 f = fa[lt];
        f.x = fmaxf(f.x, 0.f) + EPSF;
        f.y = fmaxf(f.y, 0.f) + EPSF;
        f.z = fmaxf(f.z, 0.f) + EPSF;
        f.w = fmaxf(f.w, 0.f) + EPSF;
        kpart += f.x + f.y + f.z + f.w;
        bf16x4 w = {(bf16)f.x, (bf16)f.y, (bf16)f.z, (bf16)f.w};
        *(bf16x4*)&kpw[c * STR + lt * 16 + g * 4] = w;
      }
      ksum_acc[mt] += kpart;
#pragma unroll
      for (int s = 0; s < 2; ++s) {
        bf16x8 kb = *(const bf16x8*)&kpw[c * STR + s * 32 + g * 8];
#pragma unroll
        for (int dt = 0; dt < 4; ++dt)
          acc[dt][mt] = __builtin_amdgcn_mfma_f32_16x16x32_bf16(va[dt][s], kb, acc[dt][mt], 0, 0, 0);
      }
    }
  }

#pragma unroll
  for (int mt = 0; mt < 5; ++mt) {
    const int m = wid * 80 + mt * 16 + c;
#pragma unroll
    for (int dt = 0; dt < 4; ++dt) {
      f32x4 a = acc[dt][mt];
      const int db = dt * 16 + g * 4;
      atomicAdd(&kv_ws[((size_t)bh * 64 + db + 0) * MP + m], a.x);
      atomicAdd(&kv_ws[((size_t)bh * 64 + db + 1) * MP + m], a.y);
      atomicAdd(&kv_ws[((size_t)bh * 64 + db + 2) * MP + m], a.z);
      atomicAdd(&kv_ws[((size_t)bh * 64 + db + 3) * MP + m], a.w);
    }
    float r = ksum_acc[mt];
    r += __shfl_xor(r, 16);
    r += __shfl_xor(r, 32);
    if (g == 0) atomicAdd(&ksum_ws[bh * MP + m], r);
  }
}

// ---------------------------------------------------------------------------
// Kernel C: one-shot f32 -> bf16 conversion of kv workspace and proj
// ---------------------------------------------------------------------------
__global__ __launch_bounds__(256) void perf_cvt(
    const float* __restrict__ kv_ws, const float* __restrict__ proj,
    bf16* __restrict__ kv_b, bf16* __restrict__ pj_b)
{
  const int KV4 = BHN * DN * MP / 4;  // 327680
  const int PJ4 = MP * DN / 4;        // 5120
  int idx = blockIdx.x * 256 + threadIdx.x;
  if (idx < KV4) {
    f4 v = reinterpret_cast<const f4*>(kv_ws)[idx];
    bf16x4 w = {(bf16)v.x, (bf16)v.y, (bf16)v.z, (bf16)v.w};
    *(bf16x4*)&kv_b[idx * 4] = w;
  } else if (idx < KV4 + PJ4) {
    int p = idx - KV4;
    int m = p >> 4;
    f4 v = {0.f, 0.f, 0.f, 0.f};
    if (m < MN) v = reinterpret_cast<const f4*>(proj)[p];
    bf16x4 w = {(bf16)v.x, (bf16)v.y, (bf16)v.z, (bf16)v.w};
    *(bf16x4*)&pj_b[p * 4] = w;
  }
}

// ---------------------------------------------------------------------------
// Kernel B: qp = relu(Q·projT)+eps; d = qp·ksum; out[l][d] = (qp·kv)[l][d]/d[l]
// grid (32 l-tiles of 128, 64 bh) x 256 threads; wave w owns l in [32w, 32w+32)
// All staged operands pre-converted bf16; chunk prefetch into registers.
// ---------------------------------------------------------------------------
__global__ __launch_bounds__(256, 2) void perf_out_mfma(
    const float* __restrict__ qg, const bf16* __restrict__ pjb,
    const bf16* __restrict__ kvb, const float* __restrict__ ksum_ws,
    float* __restrict__ outg)
{
  __shared__ __align__(16) bf16 q_lds[128 * STR];     // [l][d]
  __shared__ __align__(16) bf16 pj_lds[64 * STR];     // chunk [m][d]
  __shared__ __align__(16) bf16 kv_lds[64 * STR];     // chunk [d][m]
  __shared__ __align__(16) bf16 qp_lds[4 * 32 * STR]; // per-wave [32 l][64 m]
  __shared__ float ksum_lds[64];
  __shared__ float d_lds[128];

  const int t    = threadIdx.x;
  const int wid  = t >> 6;
  const int lane = t & 63;
  const int c    = lane & 15;
  const int g    = lane >> 4;
  const int lb   = blockIdx.x;   // 0..31
  const int bh   = blockIdx.y;   // 0..63
  const int l0   = lb * 128;

  // stage Q tile (f32 -> bf16), once
  {
    const f4* qg4 = reinterpret_cast<const f4*>(qg) + ((size_t)bh * LN + l0) * 16;
    for (int idx = t; idx < 128 * 16; idx += 256) {
      int l = idx >> 4, d4 = idx & 15;
      f4 val = qg4[l * 16 + d4];
      bf16x4 w = {(bf16)val.x, (bf16)val.y, (bf16)val.z, (bf16)val.w};
      *(bf16x4*)&q_lds[l * STR + d4 * 4] = w;
    }
  }
  __syncthreads();

  // loop-invariant Q fragments: wave's 2 l-frags x 2 k-slices
  bf16x8 qb[2][2];
#pragma unroll
  for (int lf = 0; lf < 2; ++lf)
#pragma unroll
    for (int s = 0; s < 2; ++s)
      qb[lf][s] = *(const bf16x8*)&q_lds[(wid * 32 + lf * 16 + c) * STR + s * 32 + g * 8];

  f32x4 oacc[2][4];
#pragma unroll
  for (int lf = 0; lf < 2; ++lf)
#pragma unroll
    for (int dt = 0; dt < 4; ++dt) oacc[lf][dt] = (f32x4){0.f, 0.f, 0.f, 0.f};
  float dp[2] = {0.f, 0.f};

  bf16* qpw = qp_lds + wid * 32 * STR;

  // chunk prefetch registers
  bf16x8 pjreg[2], kvreg[2];
  float ksreg = 0.f;
  auto LOADCHUNK = [&](int m0) {
#pragma unroll
    for (int i = 0; i < 2; ++i) {
      int idx = t + i * 256;
      int r = idx >> 3, c8 = idx & 7;
      pjreg[i] = *(const bf16x8*)&pjb[(m0 + r) * 64 + c8 * 8];
      kvreg[i] = *(const bf16x8*)&kvb[((size_t)bh * 64 + r) * MP + m0 + c8 * 8];
    }
    if (t < 64) ksreg = ksum_ws[bh * MP + m0 + t];
  };
  auto WRITECHUNK = [&]() {
#pragma unroll
    for (int i = 0; i < 2; ++i) {
      int idx = t + i * 256;
      int r = idx >> 3, c8 = idx & 7;
      *(bf16x8*)&pj_lds[r * STR + c8 * 8] = pjreg[i];
      *(bf16x8*)&kv_lds[r * STR + c8 * 8] = kvreg[i];
    }
    if (t < 64) ksum_lds[t] = ksreg;
  };

  LOADCHUNK(0);

  for (int mc = 0; mc < 5; ++mc) {
    __syncthreads();   // previous chunk fully consumed
    WRITECHUNK();
    __syncthreads();   // chunk ready
    if (mc < 4) LOADCHUNK((mc + 1) * 64);  // overlap with MFMA phase

#pragma unroll
    for (int lf = 0; lf < 2; ++lf) {
      // feature: C2[m][l] = proj·QT for this wave's 16 l-cols
#pragma unroll
      for (int mt = 0; mt < 4; ++mt) {
        bf16x8 pa0 = *(const bf16x8*)&pj_lds[(mt * 16 + c) * STR + g * 8];
        bf16x8 pa1 = *(const bf16x8*)&pj_lds[(mt * 16 + c) * STR + 32 + g * 8];
        f32x4 fa = (f32x4){0.f, 0.f, 0.f, 0.f};
        fa = __builtin_amdgcn_mfma_f32_16x16x32_bf16(pa0, qb[lf][0], fa, 0, 0, 0);
        fa = __builtin_amdgcn_mfma_f32_16x16x32_bf16(pa1, qb[lf][1], fa, 0, 0, 0);
        fa.x = fmaxf(fa.x, 0.f) + EPSF;
        fa.y = fmaxf(fa.y, 0.f) + EPSF;
        fa.z = fmaxf(fa.z, 0.f) + EPSF;
        fa.w = fmaxf(fa.w, 0.f) + EPSF;
        const int mb = mt * 16 + g * 4;
        dp[lf] += fa.x * ksum_lds[mb + 0] + fa.y * ksum_lds[mb + 1] +
                  fa.z * ksum_lds[mb + 2] + fa.w * ksum_lds[mb + 3];
        bf16x4 w = {(bf16)fa.x, (bf16)fa.y, (bf16)fa.z, (bf16)fa.w};
        *(bf16x4*)&qpw[(lf * 16 + c) * STR + mb] = w;
      }
      // out: A = qp[l][m], B = kvT[d][m]
#pragma unroll
      for (int s = 0; s < 2; ++s) {
        bf16x8 qa = *(const bf16x8*)&qpw[(lf * 16 + c) * STR + s * 32 + g * 8];
#pragma unroll
        for (int dt = 0; dt < 4; ++dt) {
          bf16x8 kb = *(const bf16x8*)&kv_lds[(dt * 16 + c) * STR + s * 32 + g * 8];
          oacc[lf][dt] = __builtin_amdgcn_mfma_f32_16x16x32_bf16(qa, kb, oacc[lf][dt], 0, 0, 0);
        }
      }
    }
  }

#pragma unroll
  for (int lf = 0; lf < 2; ++lf) {
    float r = dp[lf];
    r += __shfl_xor(r, 16);
    r += __shfl_xor(r, 32);
    if (g == 0) d_lds[wid * 32 + lf * 16 + c] = r;
  }
  __syncthreads();

  float* ob = outg + ((size_t)bh * LN + l0) * DN;
#pragma unroll
  for (int lf = 0; lf < 2; ++lf) {
    const int lrow = wid * 32 + lf * 16 + g * 4;
    float dinv0 = 1.f / d_lds[lrow + 0];
    float dinv1 = 1.f / d_lds[lrow + 1];
    float dinv2 = 1.f / d_lds[lrow + 2];
    float dinv3 = 1.f / d_lds[lrow + 3];
#pragma unroll
    for (int dt = 0; dt < 4; ++dt) {
      f32x4 a = oacc[lf][dt];
      const int dcol = dt * 16 + c;
      ob[(size_t)(lrow + 0) * 64 + dcol] = a.x * dinv0;
      ob[(size_t)(lrow + 1) * 64 + dcol] = a.y * dinv1;
      ob[(size_t)(lrow + 2) * 64 + dcol] = a.z * dinv2;
      ob[(size_t)(lrow + 3) * 64 + dcol] = a.w * dinv3;
    }
  }
}

// ---------------------------------------------------------------------------
extern "C" void kernel_launch(void* const* d_in, const int* in_sizes, int n_in,
                              void* d_out, int out_size, void* d_ws, size_t ws_size,
                              hipStream_t stream)
{
  const float* q    = (const float*)d_in[0];
  const float* k    = (const float*)d_in[1];
  const float* v    = (const float*)d_in[2];
  const float* proj = (const float*)d_in[3];
  float* out     = (float*)d_out;

  float* kv_ws   = (float*)d_ws;                        // [64][64][320] f32
  float* ksum_ws = kv_ws + (size_t)BHN * DN * MP;       // [64][320] f32
  bf16*  kv_b    = (bf16*)(ksum_ws + (size_t)BHN * MP); // [64][64][320] bf16
  bf16*  pj_b    = kv_b + (size_t)BHN * DN * MP;        // [320][64] bf16

  size_t zero_bytes = ((size_t)BHN * DN * MP + (size_t)BHN * MP) * sizeof(float);
  hipMemsetAsync(d_ws, 0, zero_bytes, stream);

  perf_kv_mfma<<<dim3(8, BHN), 256, 0, stream>>>(k, v, proj, kv_ws, ksum_ws);

  const int CVT_ITEMS = BHN * DN * MP / 4 + MP * DN / 4;
  perf_cvt<<<(CVT_ITEMS + 255) / 256, 256, 0, stream>>>(kv_ws, proj, kv_b, pj_b);

  perf_out_mfma<<<dim3(LN / 128, BHN), 256, 0, stream>>>(q, pj_b, kv_b, ksum_ws, out);
}

// Round 4
// 124.013 us; speedup vs baseline: 1.8263x; 1.8263x over previous
//
#include <hip/hip_runtime.h>

typedef __bf16 bf16;
typedef bf16 bf16x2 __attribute__((ext_vector_type(2)));
typedef bf16 bf16x4 __attribute__((ext_vector_type(4)));
typedef bf16 bf16x8 __attribute__((ext_vector_type(8)));
typedef float f32x4 __attribute__((ext_vector_type(4)));
typedef float f32x16 __attribute__((ext_vector_type(16)));
typedef unsigned int u32;
typedef u32 u32x4 __attribute__((ext_vector_type(4)));
typedef float4 f4;

constexpr int BHN = 64;   // B*H
constexpr int LN  = 4096;
constexpr int DN  = 64;
constexpr int MN  = 266;  // real feature rows
constexpr int MP  = 320;  // padded to 5*64 (zero proj rows; numerically negligible)
constexpr int STR = 72;   // LDS row stride in bf16 (144B)
constexpr int KVS = 328;  // kv LDS row stride in bf16 (656B)
#define EPSF 1e-3f

#define MFMA32(A, B, C) __builtin_amdgcn_mfma_f32_32x32x16_bf16(A, B, C, 0, 0, 0)

__device__ __forceinline__ u32 cvt_pk_bf16(float lo, float hi) {
  u32 r;
  asm("v_cvt_pk_bf16_f32 %0, %1, %2" : "=v"(r) : "v"(lo), "v"(hi));
  return r;
}

// ---------------------------------------------------------------------------
// Kernel A (round-2 proven form): kvT[bh][d][m] += V^T·kp, ksum[bh][m] += sum kp
// grid (8 l-chunks, 64 bh) x 256 threads; wave w owns m in [80w, 80w+80)
// ---------------------------------------------------------------------------
__global__ __launch_bounds__(256, 2) void perf_kv_mfma(
    const float* __restrict__ kg, const float* __restrict__ vg,
    const float* __restrict__ proj, float* __restrict__ kv_ws,
    float* __restrict__ ksum_ws)
{
  __shared__ __align__(16) bf16 proj_lds[MP * STR];   // [m][d]
  __shared__ __align__(16) bf16 k_lds[64 * STR];      // [l][d]
  __shared__ __align__(16) bf16 vt_lds[64 * STR];     // [d][l]
  __shared__ __align__(16) bf16 kp_lds[4 * 16 * STR]; // per-wave [16 m][64 l]

  const int t    = threadIdx.x;
  const int wid  = t >> 6;
  const int lane = t & 63;
  const int c    = lane & 15;
  const int g    = lane >> 4;
  const int lsp  = blockIdx.x;  // 0..7
  const int bh   = blockIdx.y;  // 0..63

  const f4* projv = reinterpret_cast<const f4*>(proj);
  for (int idx = t; idx < MP * 16; idx += 256) {
    int m = idx >> 4, d4 = idx & 15;
    f4 val = {0.f, 0.f, 0.f, 0.f};
    if (m < MN) val = projv[m * 16 + d4];
    bf16x4 w = {(bf16)val.x, (bf16)val.y, (bf16)val.z, (bf16)val.w};
    *(bf16x4*)&proj_lds[m * STR + d4 * 4] = w;
  }

  f32x4 acc[4][5];
#pragma unroll
  for (int dt = 0; dt < 4; ++dt)
#pragma unroll
    for (int mt = 0; mt < 5; ++mt) acc[dt][mt] = (f32x4){0.f, 0.f, 0.f, 0.f};
  float ksum_acc[5] = {0.f, 0.f, 0.f, 0.f, 0.f};

  bf16* kpw = kp_lds + wid * 16 * STR;

  for (int ls = 0; ls < 8; ++ls) {
    const int l0 = (lsp * 8 + ls) * 64;
    __syncthreads();
    {
      const f4* kg4 = reinterpret_cast<const f4*>(kg) + ((size_t)bh * LN + l0) * 16;
      for (int idx = t; idx < 64 * 16; idx += 256) {
        int l = idx >> 4, d4 = idx & 15;
        f4 val = kg4[l * 16 + d4];
        bf16x4 w = {(bf16)val.x, (bf16)val.y, (bf16)val.z, (bf16)val.w};
        *(bf16x4*)&k_lds[l * STR + d4 * 4] = w;
      }
    }
    {
      const float* vbase = vg + ((size_t)bh * LN + l0) * DN;
      const int d = t & 63, grp = t >> 6;
#pragma unroll
      for (int i = 0; i < 4; ++i) {
        int lb = grp * 16 + i * 4;
        float x0 = vbase[(lb + 0) * 64 + d];
        float x1 = vbase[(lb + 1) * 64 + d];
        float x2 = vbase[(lb + 2) * 64 + d];
        float x3 = vbase[(lb + 3) * 64 + d];
        bf16x4 w = {(bf16)x0, (bf16)x1, (bf16)x2, (bf16)x3};
        *(bf16x4*)&vt_lds[d * STR + lb] = w;
      }
    }
    __syncthreads();

    bf16x8 va[4][2], ka[4][2];
#pragma unroll
    for (int dt = 0; dt < 4; ++dt)
#pragma unroll
      for (int s = 0; s < 2; ++s)
        va[dt][s] = *(const bf16x8*)&vt_lds[(dt * 16 + c) * STR + s * 32 + g * 8];
#pragma unroll
    for (int lt = 0; lt < 4; ++lt)
#pragma unroll
      for (int s = 0; s < 2; ++s)
        ka[lt][s] = *(const bf16x8*)&k_lds[(lt * 16 + c) * STR + s * 32 + g * 8];

#pragma unroll
    for (int mt = 0; mt < 5; ++mt) {
      const int m0 = wid * 80 + mt * 16;
      bf16x8 pb0 = *(const bf16x8*)&proj_lds[(m0 + c) * STR + g * 8];
      bf16x8 pb1 = *(const bf16x8*)&proj_lds[(m0 + c) * STR + 32 + g * 8];
      f32x4 fa[4];
#pragma unroll
      for (int lt = 0; lt < 4; ++lt) {
        fa[lt] = (f32x4){0.f, 0.f, 0.f, 0.f};
        fa[lt] = __builtin_amdgcn_mfma_f32_16x16x32_bf16(ka[lt][0], pb0, fa[lt], 0, 0, 0);
        fa[lt] = __builtin_amdgcn_mfma_f32_16x16x32_bf16(ka[lt][1], pb1, fa[lt], 0, 0, 0);
      }
      float kpart = 0.f;
#pragma unroll
      for (int lt = 0; lt < 4; ++lt) {
        f32x4 f = fa[lt];
        f.x = fmaxf(f.x, 0.f) + EPSF;
        f.y = fmaxf(f.y, 0.f) + EPSF;
        f.z = fmaxf(f.z, 0.f) + EPSF;
        f.w = fmaxf(f.w, 0.f) + EPSF;
        kpart += f.x + f.y + f.z + f.w;
        bf16x4 w = {(bf16)f.x, (bf16)f.y, (bf16)f.z, (bf16)f.w};
        *(bf16x4*)&kpw[c * STR + lt * 16 + g * 4] = w;
      }
      ksum_acc[mt] += kpart;
#pragma unroll
      for (int s = 0; s < 2; ++s) {
        bf16x8 kb = *(const bf16x8*)&kpw[c * STR + s * 32 + g * 8];
#pragma unroll
        for (int dt = 0; dt < 4; ++dt)
          acc[dt][mt] = __builtin_amdgcn_mfma_f32_16x16x32_bf16(va[dt][s], kb, acc[dt][mt], 0, 0, 0);
      }
    }
  }

#pragma unroll
  for (int mt = 0; mt < 5; ++mt) {
    const int m = wid * 80 + mt * 16 + c;
#pragma unroll
    for (int dt = 0; dt < 4; ++dt) {
      f32x4 a = acc[dt][mt];
      const int db = dt * 16 + g * 4;
      atomicAdd(&kv_ws[((size_t)bh * 64 + db + 0) * MP + m], a.x);
      atomicAdd(&kv_ws[((size_t)bh * 64 + db + 1) * MP + m], a.y);
      atomicAdd(&kv_ws[((size_t)bh * 64 + db + 2) * MP + m], a.z);
      atomicAdd(&kv_ws[((size_t)bh * 64 + db + 3) * MP + m], a.w);
    }
    float r = ksum_acc[mt];
    r += __shfl_xor(r, 16);
    r += __shfl_xor(r, 32);
    if (g == 0) atomicAdd(&ksum_ws[bh * MP + m], r);
  }
}

// ---------------------------------------------------------------------------
// Kernel C: one-shot f32 -> bf16 conversion of kv workspace and proj
// ---------------------------------------------------------------------------
__global__ __launch_bounds__(256) void perf_cvt(
    const float* __restrict__ kv_ws, const float* __restrict__ proj,
    bf16* __restrict__ kv_b, bf16* __restrict__ pj_b)
{
  const int KV4 = BHN * DN * MP / 4;  // 327680
  const int PJ4 = MP * DN / 4;        // 5120
  int idx = blockIdx.x * 256 + threadIdx.x;
  if (idx < KV4) {
    f4 v = reinterpret_cast<const f4*>(kv_ws)[idx];
    bf16x4 w = {(bf16)v.x, (bf16)v.y, (bf16)v.z, (bf16)v.w};
    *(bf16x4*)&kv_b[idx * 4] = w;
  } else if (idx < KV4 + PJ4) {
    int p = idx - KV4;
    int m = p >> 4;
    f4 v = {0.f, 0.f, 0.f, 0.f};
    if (m < MN) v = reinterpret_cast<const f4*>(proj)[p];
    bf16x4 w = {(bf16)v.x, (bf16)v.y, (bf16)v.z, (bf16)v.w};
    *(bf16x4*)&pj_b[p * 4] = w;
  }
}

// ---------------------------------------------------------------------------
// Kernel B (32x32 MFMA, whole-M LDS-resident, barrier-free K loop):
//   qp = relu(Q·projT)+eps (in regs); d = qp·ksum; out = (qp·kvT)/d
// grid (4 lb, 64 bh) x 512 threads (8 waves, 1 block/CU). Each wave: 64 l/round,
// 2 rounds. T12: cvt_pk + permlane32_swap turn feature C-frags into A-frags.
// ---------------------------------------------------------------------------
__global__ __launch_bounds__(512, 2) void perf_out_mfma32(
    const float* __restrict__ qg, const bf16* __restrict__ pjb,
    const bf16* __restrict__ kvb, const float* __restrict__ ksum_ws,
    float* __restrict__ outg)
{
  __shared__ __align__(16) bf16 pj_lds[MP * STR];   // [m][d]   46080 B
  __shared__ __align__(16) bf16 kv_lds[DN * KVS];   // [d][m]   41984 B
  __shared__ __align__(16) float ksum_lds[MP];      //           1280 B
  __shared__ float dp_lds[8 * 64];                  //           2048 B

  const int t    = threadIdx.x;
  const int wid  = t >> 6;
  const int lane = t & 63;
  const int ln31 = lane & 31;
  const int hi   = lane >> 5;
  const int bh   = blockIdx.y;
  const int lbase = blockIdx.x * 1024;

  // one-time staging: pj (320x64 bf16), kvT (64x320 bf16), ksum (320 f32)
  for (int idx = t; idx < MP * 8; idx += 512) {
    int r = idx >> 3, c8 = idx & 7;
    *(bf16x8*)&pj_lds[r * STR + c8 * 8] = *(const bf16x8*)&pjb[r * 64 + c8 * 8];
  }
  for (int idx = t; idx < DN * 40; idx += 512) {
    int r = idx / 40, cc = idx % 40;
    *(bf16x8*)&kv_lds[r * KVS + cc * 8] =
        *(const bf16x8*)&kvb[((size_t)bh * DN + r) * MP + cc * 8];
  }
  if (t < MP) ksum_lds[t] = ksum_ws[bh * MP + t];
  __syncthreads();  // the only block barrier

  for (int rnd = 0; rnd < 2; ++rnd) {
    const int lw = lbase + rnd * 512 + wid * 64;

    // Q B-fragments from global (f32 -> bf16): col l = ln31, k(d) = ks*16+hi*8
    bf16x8 qb[2][4];
#pragma unroll
    for (int lt = 0; lt < 2; ++lt)
#pragma unroll
      for (int ks = 0; ks < 4; ++ks) {
        const float* qp_ = qg + ((size_t)bh * LN + lw + lt * 32 + ln31) * 64 + ks * 16 + hi * 8;
        f4 a = *(const f4*)qp_;
        f4 b = *(const f4*)(qp_ + 4);
        qb[lt][ks] = (bf16x8){(bf16)a.x, (bf16)a.y, (bf16)a.z, (bf16)a.w,
                              (bf16)b.x, (bf16)b.y, (bf16)b.z, (bf16)b.w};
      }

    f32x16 oc[2][2];  // [lt][dt]: out rows l, cols d=dt*32+ln31
    oc[0][0] = (f32x16){}; oc[0][1] = (f32x16){};
    oc[1][0] = (f32x16){}; oc[1][1] = (f32x16){};
    float dp[2] = {0.f, 0.f};

    for (int mc = 0; mc < 5; ++mc) {
      // feature: C2[m][l] = pj·Q^T for 64 m x 64 l (2 mt x 2 lt tiles)
      f32x16 c2[2][2];  // [lt][mt]
      c2[0][0] = (f32x16){}; c2[0][1] = (f32x16){};
      c2[1][0] = (f32x16){}; c2[1][1] = (f32x16){};
#pragma unroll
      for (int ks = 0; ks < 4; ++ks) {
        bf16x8 pa0 = *(const bf16x8*)&pj_lds[(mc * 64 + ln31) * STR + ks * 16 + hi * 8];
        bf16x8 pa1 = *(const bf16x8*)&pj_lds[(mc * 64 + 32 + ln31) * STR + ks * 16 + hi * 8];
        c2[0][0] = MFMA32(pa0, qb[0][ks], c2[0][0]);
        c2[1][0] = MFMA32(pa0, qb[1][ks], c2[1][0]);
        c2[0][1] = MFMA32(pa1, qb[0][ks], c2[0][1]);
        c2[1][1] = MFMA32(pa1, qb[1][ks], c2[1][1]);
      }
#pragma unroll
      for (int mt = 0; mt < 2; ++mt) {
        const int mb = mc * 64 + mt * 32 + 4 * hi;  // lane's m rows: mb + j + 8*rg
        f32x4 kq0 = *(const f32x4*)&ksum_lds[mb + 0];
        f32x4 kq1 = *(const f32x4*)&ksum_lds[mb + 8];
        f32x4 kq2 = *(const f32x4*)&ksum_lds[mb + 16];
        f32x4 kq3 = *(const f32x4*)&ksum_lds[mb + 24];
        bf16x8 A[2][2];  // [lt][kk]
#pragma unroll
        for (int lt = 0; lt < 2; ++lt) {
          f32x16 f = c2[lt][mt];
#pragma unroll
          for (int i = 0; i < 16; ++i) f[i] = fmaxf(f[i], 0.f) + EPSF;
          dp[lt] += f[0] * kq0[0] + f[1] * kq0[1] + f[2] * kq0[2] + f[3] * kq0[3]
                  + f[4] * kq1[0] + f[5] * kq1[1] + f[6] * kq1[2] + f[7] * kq1[3]
                  + f[8] * kq2[0] + f[9] * kq2[1] + f[10] * kq2[2] + f[11] * kq2[3]
                  + f[12] * kq3[0] + f[13] * kq3[1] + f[14] * kq3[2] + f[15] * kq3[3];
          // T12: pack f32 pairs to bf16 words, permlane-swap to A-operand layout
          u32 w0 = cvt_pk_bf16(f[0], f[1]);
          u32 w1 = cvt_pk_bf16(f[2], f[3]);
          u32 w2 = cvt_pk_bf16(f[4], f[5]);
          u32 w3 = cvt_pk_bf16(f[6], f[7]);
          u32 w4 = cvt_pk_bf16(f[8], f[9]);
          u32 w5 = cvt_pk_bf16(f[10], f[11]);
          u32 w6 = cvt_pk_bf16(f[12], f[13]);
          u32 w7 = cvt_pk_bf16(f[14], f[15]);
          asm("v_permlane32_swap_b32 %0, %1" : "+v"(w0), "+v"(w2));
          asm("v_permlane32_swap_b32 %0, %1" : "+v"(w1), "+v"(w3));
          asm("v_permlane32_swap_b32 %0, %1" : "+v"(w4), "+v"(w6));
          asm("v_permlane32_swap_b32 %0, %1" : "+v"(w5), "+v"(w7));
          u32x4 a0 = {w0, w1, w2, w3};
          u32x4 a1 = {w4, w5, w6, w7};
          A[lt][0] = __builtin_bit_cast(bf16x8, a0);
          A[lt][1] = __builtin_bit_cast(bf16x8, a1);
        }
        // out: oc[l][d] += qp[l][m-slice] · kvT[d][m-slice]
#pragma unroll
        for (int kk = 0; kk < 2; ++kk) {
          const int mo = mc * 64 + (mt * 2 + kk) * 16 + hi * 8;
          bf16x8 kb0 = *(const bf16x8*)&kv_lds[ln31 * KVS + mo];
          bf16x8 kb1 = *(const bf16x8*)&kv_lds[(32 + ln31) * KVS + mo];
          oc[0][0] = MFMA32(A[0][kk], kb0, oc[0][0]);
          oc[1][0] = MFMA32(A[1][kk], kb0, oc[1][0]);
          oc[0][1] = MFMA32(A[0][kk], kb1, oc[0][1]);
          oc[1][1] = MFMA32(A[1][kk], kb1, oc[1][1]);
        }
      }
    }

    // denominator: lane pair (p, p+32) holds complementary m halves of col l
#pragma unroll
    for (int lt = 0; lt < 2; ++lt) {
      float r = dp[lt];
      r += __shfl_xor(r, 32);
      dp_lds[wid * 64 + lt * 32 + ln31] = r;  // wave-private; no block barrier
    }
#pragma unroll
    for (int lt = 0; lt < 2; ++lt) {
#pragma unroll
      for (int rg = 0; rg < 4; ++rg) {
        f32x4 dv = *(const f32x4*)&dp_lds[wid * 64 + lt * 32 + 8 * rg + 4 * hi];
        f32x4 di = {1.f / dv[0], 1.f / dv[1], 1.f / dv[2], 1.f / dv[3]};
#pragma unroll
        for (int dt = 0; dt < 2; ++dt) {
#pragma unroll
          for (int j = 0; j < 4; ++j) {
            int l = lw + lt * 32 + 8 * rg + 4 * hi + j;
            outg[((size_t)bh * LN + l) * DN + dt * 32 + ln31] = oc[lt][dt][4 * rg + j] * di[j];
          }
        }
      }
    }
  }
}

// ---------------------------------------------------------------------------
extern "C" void kernel_launch(void* const* d_in, const int* in_sizes, int n_in,
                              void* d_out, int out_size, void* d_ws, size_t ws_size,
                              hipStream_t stream)
{
  const float* q    = (const float*)d_in[0];
  const float* k    = (const float*)d_in[1];
  const float* v    = (const float*)d_in[2];
  const float* proj = (const float*)d_in[3];
  float* out     = (float*)d_out;

  float* kv_ws   = (float*)d_ws;                        // [64][64][320] f32
  float* ksum_ws = kv_ws + (size_t)BHN * DN * MP;       // [64][320] f32
  bf16*  kv_b    = (bf16*)(ksum_ws + (size_t)BHN * MP); // [64][64][320] bf16
  bf16*  pj_b    = kv_b + (size_t)BHN * DN * MP;        // [320][64] bf16

  size_t zero_bytes = ((size_t)BHN * DN * MP + (size_t)BHN * MP) * sizeof(float);
  hipMemsetAsync(d_ws, 0, zero_bytes, stream);

  perf_kv_mfma<<<dim3(8, BHN), 256, 0, stream>>>(k, v, proj, kv_ws, ksum_ws);

  const int CVT_ITEMS = BHN * DN * MP / 4 + MP * DN / 4;
  perf_cvt<<<(CVT_ITEMS + 255) / 256, 256, 0, stream>>>(kv_ws, proj, kv_b, pj_b);

  perf_out_mfma32<<<dim3(4, BHN), 512, 0, stream>>>(q, pj_b, kv_b, ksum_ws, out);
}